// Round 5
// baseline (302.300 us; speedup 1.0000x reference)
//
#include <hip/hip_runtime.h>
#include <hip/hip_bf16.h>
#include <hip/hip_fp16.h>

// Trilinear resample, ZERO boundary.
// inputs:      [B=2, S=144, S, S, C=2]  float32
// deformation: [B=2, S, S, S, 3]        float32 (absolute voxel coords)
// output:      [B=2, S, S, S, C=2]      float32
//
// Deformation is spatially random => every sample is a random 64B-line fill.
// Cell table (8 corners x 2ch fp16 = 32 B/cell) => ONE line per sample.
// Round 5: 4 voxels/thread in the gather kernel to quadruple per-wave MLP
// (round-4 evidence: fetch rate pinned at ~3 TB/s regardless of L3
// residency => latency/MLP-bound, not locality-bound).

#define S_DIM   144
#define SS_DIM  (144 * 144)
#define SSS_DIM (144 * 144 * 144)
#define C_DIM   2
#define VPT     4   // voxels per thread in gather kernel

__device__ __forceinline__ unsigned pack2(float a, float b) {
    __half2 h = __floats2half2_rn(a, b);
    return *reinterpret_cast<unsigned*>(&h);
}
__device__ __forceinline__ float2 unpack2(unsigned u) {
    __half2 h = *reinterpret_cast<__half2*>(&u);
    return __half22float2(h);
}

// K1: build per-cell corner table, both batches. One thread per cell.
// Record: 32 B = 8 corners (order 000,001,010,011,100,101,110,111),
// each corner = half2(ch0, ch1).
__global__ __launch_bounds__(256) void build_cell_table(
    const float* __restrict__ inp, uint4* __restrict__ table, int n_cells)
{
    int t = blockIdx.x * blockDim.x + threadIdx.x;
    if (t >= n_cells) return;

    const int b = (t >= SSS_DIM) ? 1 : 0;
    int r = t - b * SSS_DIM;
    const int x = r / SS_DIM;
    r -= x * SS_DIM;
    const int y = r / S_DIM;
    const int z = r - y * S_DIM;

    const int x1 = min(x + 1, S_DIM - 1);
    const int y1 = min(y + 1, S_DIM - 1);
    const int z1 = min(z + 1, S_DIM - 1);

    const float* vol = inp + (size_t)b * SSS_DIM * C_DIM;
    auto ld = [&](int xx, int yy, int zz) -> float2 {
        return *reinterpret_cast<const float2*>(
            vol + (size_t)(xx * SS_DIM + yy * S_DIM + zz) * C_DIM);
    };

    const float2 v000 = ld(x,  y,  z ), v001 = ld(x,  y,  z1);
    const float2 v010 = ld(x,  y1, z ), v011 = ld(x,  y1, z1);
    const float2 v100 = ld(x1, y,  z ), v101 = ld(x1, y,  z1);
    const float2 v110 = ld(x1, y1, z ), v111 = ld(x1, y1, z1);

    uint4 lo, hi;
    lo.x = pack2(v000.x, v000.y);
    lo.y = pack2(v001.x, v001.y);
    lo.z = pack2(v010.x, v010.y);
    lo.w = pack2(v011.x, v011.y);
    hi.x = pack2(v100.x, v100.y);
    hi.y = pack2(v101.x, v101.y);
    hi.z = pack2(v110.x, v110.y);
    hi.w = pack2(v111.x, v111.y);

    table[(size_t)t * 2]     = lo;
    table[(size_t)t * 2 + 1] = hi;
}

// K2: VPT voxels per thread (strided by n_thr so every load/store stays
// coalesced). All table loads issued before any unpack -> VPT independent
// random lines in flight per lane.
__global__ __launch_bounds__(256) void resample_from_table_mlp(
    const uint4* __restrict__ table, const float* __restrict__ def,
    float* __restrict__ out, int n_vox, int n_thr)
{
    int t = blockIdx.x * blockDim.x + threadIdx.x;
    if (t >= n_thr) return;

    int v[VPT];
    bool act[VPT];
    float dx[VPT], dy[VPT], dz[VPT];
#pragma unroll
    for (int k = 0; k < VPT; ++k) {
        v[k] = t + k * n_thr;
        act[k] = v[k] < n_vox;
        const size_t d = (size_t)(act[k] ? v[k] : 0) * 3;
        dx[k] = def[d + 0];
        dy[k] = def[d + 1];
        dz[k] = def[d + 2];
    }

    size_t cell2[VPT];
    float ax0[VPT], ax1[VPT], ay0[VPT], ay1[VPT], az0[VPT], az1[VPT];
#pragma unroll
    for (int k = 0; k < VPT; ++k) {
        const float fx = floorf(dx[k]), fy = floorf(dy[k]), fz = floorf(dz[k]);
        const int ix = (int)fx, iy = (int)fy, iz = (int)fz;
        const float tx = dx[k] - fx, ty = dy[k] - fy, tz = dz[k] - fz;

        // ZERO boundary folded into 1-D weights.
        ax0[k] = (ix     >= 0 && ix     < S_DIM) ? (1.0f - tx) : 0.0f;
        ax1[k] = (ix + 1 >= 0 && ix + 1 < S_DIM) ? tx          : 0.0f;
        ay0[k] = (iy     >= 0 && iy     < S_DIM) ? (1.0f - ty) : 0.0f;
        ay1[k] = (iy + 1 >= 0 && iy + 1 < S_DIM) ? ty          : 0.0f;
        az0[k] = (iz     >= 0 && iz     < S_DIM) ? (1.0f - tz) : 0.0f;
        az1[k] = (iz + 1 >= 0 && iz + 1 < S_DIM) ? tz          : 0.0f;

        const int cx = min(max(ix, 0), S_DIM - 1);
        const int cy = min(max(iy, 0), S_DIM - 1);
        const int cz = min(max(iz, 0), S_DIM - 1);
        const int b  = (v[k] >= SSS_DIM) ? 1 : 0;
        cell2[k] = ((size_t)b * SSS_DIM +
                    (size_t)(cx * SS_DIM + cy * S_DIM + cz)) * 2;
    }

    // Issue all random-line loads back-to-back.
    uint4 lo[VPT], hi[VPT];
#pragma unroll
    for (int k = 0; k < VPT; ++k) {
        lo[k] = table[cell2[k]];
        hi[k] = table[cell2[k] + 1];
    }

#pragma unroll
    for (int k = 0; k < VPT; ++k) {
        const float2 c000 = unpack2(lo[k].x), c001 = unpack2(lo[k].y);
        const float2 c010 = unpack2(lo[k].z), c011 = unpack2(lo[k].w);
        const float2 c100 = unpack2(hi[k].x), c101 = unpack2(hi[k].y);
        const float2 c110 = unpack2(hi[k].z), c111 = unpack2(hi[k].w);

        const float w000 = ax0[k] * ay0[k] * az0[k], w001 = ax0[k] * ay0[k] * az1[k];
        const float w010 = ax0[k] * ay1[k] * az0[k], w011 = ax0[k] * ay1[k] * az1[k];
        const float w100 = ax1[k] * ay0[k] * az0[k], w101 = ax1[k] * ay0[k] * az1[k];
        const float w110 = ax1[k] * ay1[k] * az0[k], w111 = ax1[k] * ay1[k] * az1[k];

        float acc0 = 0.0f, acc1 = 0.0f;
        acc0 = fmaf(w000, c000.x, acc0); acc1 = fmaf(w000, c000.y, acc1);
        acc0 = fmaf(w001, c001.x, acc0); acc1 = fmaf(w001, c001.y, acc1);
        acc0 = fmaf(w010, c010.x, acc0); acc1 = fmaf(w010, c010.y, acc1);
        acc0 = fmaf(w011, c011.x, acc0); acc1 = fmaf(w011, c011.y, acc1);
        acc0 = fmaf(w100, c100.x, acc0); acc1 = fmaf(w100, c100.y, acc1);
        acc0 = fmaf(w101, c101.x, acc0); acc1 = fmaf(w101, c101.y, acc1);
        acc0 = fmaf(w110, c110.x, acc0); acc1 = fmaf(w110, c110.y, acc1);
        acc0 = fmaf(w111, c111.x, acc0); acc1 = fmaf(w111, c111.y, acc1);

        if (act[k])
            reinterpret_cast<float2*>(out)[v[k]] = make_float2(acc0, acc1);
    }
}

// Fallback (direct gather) if d_ws is too small for the table.
__global__ __launch_bounds__(256) void resample_trilinear_zero(
    const float* __restrict__ inp, const float* __restrict__ def,
    float* __restrict__ out, int n_vox)
{
    int idx = blockIdx.x * blockDim.x + threadIdx.x;
    if (idx >= n_vox) return;

    const int S = S_DIM;
    const int b = idx / SSS_DIM;

    const float dx = def[(size_t)idx * 3 + 0];
    const float dy = def[(size_t)idx * 3 + 1];
    const float dz = def[(size_t)idx * 3 + 2];

    const float fx = floorf(dx), fy = floorf(dy), fz = floorf(dz);
    const int ix = (int)fx, iy = (int)fy, iz = (int)fz;
    const float tx = dx - fx, ty = dy - fy, tz = dz - fz;

    const float wx[2] = {1.0f - tx, tx};
    const float wy[2] = {1.0f - ty, ty};
    const float wz[2] = {1.0f - tz, tz};

    const float* vol = inp + (size_t)b * SSS_DIM * C_DIM;
    float acc0 = 0.0f, acc1 = 0.0f;

#pragma unroll
    for (int a = 0; a < 2; ++a) {
        const int x = ix + a;
        const bool vx = (x >= 0) & (x < S);
        const int xc = min(max(x, 0), S - 1);
#pragma unroll
        for (int bb = 0; bb < 2; ++bb) {
            const int y = iy + bb;
            const bool vxy = vx & (y >= 0) & (y < S);
            const int yc = min(max(y, 0), S - 1);
            const float wxy = wx[a] * wy[bb];
#pragma unroll
            for (int cc = 0; cc < 2; ++cc) {
                const int z = iz + cc;
                const bool valid = vxy & (z >= 0) & (z < S);
                const int zc = min(max(z, 0), S - 1);
                const float w = valid ? wxy * wz[cc] : 0.0f;
                const float2 val = *reinterpret_cast<const float2*>(
                    vol + (size_t)(xc * SS_DIM + yc * S + zc) * C_DIM);
                acc0 = fmaf(w, val.x, acc0);
                acc1 = fmaf(w, val.y, acc1);
            }
        }
    }
    reinterpret_cast<float2*>(out)[idx] = make_float2(acc0, acc1);
}

extern "C" void kernel_launch(void* const* d_in, const int* in_sizes, int n_in,
                              void* d_out, int out_size, void* d_ws, size_t ws_size,
                              hipStream_t stream) {
    const float* inp = (const float*)d_in[0];
    const float* def = (const float*)d_in[1];
    float* out = (float*)d_out;

    const int n_vox = out_size / C_DIM;               // B * S^3 = 5,971,968
    const int n_cells = 2 * SSS_DIM;
    const size_t table_bytes = (size_t)n_cells * 32;  // 191 MB

    const int block = 256;
    if (ws_size >= table_bytes) {
        uint4* table = (uint4*)d_ws;
        build_cell_table<<<(n_cells + block - 1) / block, block, 0, stream>>>(
            inp, table, n_cells);
        const int n_thr = (n_vox + VPT - 1) / VPT;    // divides evenly: 1,492,992
        resample_from_table_mlp<<<(n_thr + block - 1) / block, block, 0, stream>>>(
            table, def, out, n_vox, n_thr);
    } else {
        resample_trilinear_zero<<<(n_vox + block - 1) / block, block, 0, stream>>>(
            inp, def, out, n_vox);
    }
}

// Round 8
// 297.952 us; speedup vs baseline: 1.0146x; 1.0146x over previous
//
#include <hip/hip_runtime.h>
#include <hip/hip_bf16.h>
#include <hip/hip_fp16.h>

// Trilinear resample, ZERO boundary.
// inputs:      [B=2, S=144, S, S, C=2]  float32
// deformation: [B=2, S, S, S, 3]        float32 (absolute voxel coords)
// output:      [B=2, S, S, S, C=2]      float32
//
// Deformation is spatially random => every sample is a random 64B-line fill.
// Cell table (8 corners x 2ch fp16 = 32 B/cell) => ONE line per sample.
// Round 5 established K2 is at the random-line fill ceiling (~3.2 TB/s,
// invariant to MLP and L3 residency). Round 6: optimize K1 only — one thread
// builds 2 z-adjacent cells (one aligned 64B line) with float4 loads.

#define S_DIM   144
#define SS_DIM  (144 * 144)
#define SSS_DIM (144 * 144 * 144)
#define C_DIM   2

__device__ __forceinline__ unsigned pack2(float a, float b) {
    __half2 h = __floats2half2_rn(a, b);
    return *reinterpret_cast<unsigned*>(&h);
}
__device__ __forceinline__ float2 unpack2(unsigned u) {
    __half2 h = *reinterpret_cast<__half2*>(&u);
    return __half22float2(h);
}

// K1: one thread per (b, x, y, z-pair); builds cells z and z+1 (z even) and
// writes them as one contiguous, 64B-aligned line (4 x uint4).
// Record order per cell: lo = {000,001,010,011}, hi = {100,101,110,111},
// bit order (dx,dy,dz), each corner = half2(ch0,ch1).
__global__ __launch_bounds__(256) void build_cell_table_pair(
    const float* __restrict__ inp, uint4* __restrict__ table, int n_pairs)
{
    int t = blockIdx.x * blockDim.x + threadIdx.x;
    if (t >= n_pairs) return;

    const int per_b = SS_DIM * (S_DIM / 2);
    const int b = (t >= per_b) ? 1 : 0;
    int r = t - b * per_b;
    const int x = r / (S_DIM * (S_DIM / 2));
    r -= x * (S_DIM * (S_DIM / 2));
    const int y = r / (S_DIM / 2);
    const int zp = r - y * (S_DIM / 2);
    const int z = zp * 2;                      // even, 0..142

    const int x1 = min(x + 1, S_DIM - 1);
    const int y1 = min(y + 1, S_DIM - 1);
    const int z2 = min(z + 2, S_DIM - 1);      // corner z of cell z+1 (clamped)

    const float* vol = inp + (size_t)b * SSS_DIM * C_DIM;

    // Row bases (floats) for the 4 (x,y) combos.
    const size_t r00 = (size_t)(x  * SS_DIM + y  * S_DIM) * C_DIM;
    const size_t r01 = (size_t)(x  * SS_DIM + y1 * S_DIM) * C_DIM;
    const size_t r10 = (size_t)(x1 * SS_DIM + y  * S_DIM) * C_DIM;
    const size_t r11 = (size_t)(x1 * SS_DIM + y1 * S_DIM) * C_DIM;

    // Per row: float4 covers {z.c0, z.c1, z+1.c0, z+1.c1} (16B aligned since
    // z is even), float2 covers {z2.c0, z2.c1}.
    const float4 a00 = *reinterpret_cast<const float4*>(vol + r00 + (size_t)z * C_DIM);
    const float2 b00 = *reinterpret_cast<const float2*>(vol + r00 + (size_t)z2 * C_DIM);
    const float4 a01 = *reinterpret_cast<const float4*>(vol + r01 + (size_t)z * C_DIM);
    const float2 b01 = *reinterpret_cast<const float2*>(vol + r01 + (size_t)z2 * C_DIM);
    const float4 a10 = *reinterpret_cast<const float4*>(vol + r10 + (size_t)z * C_DIM);
    const float2 b10 = *reinterpret_cast<const float2*>(vol + r10 + (size_t)z2 * C_DIM);
    const float4 a11 = *reinterpret_cast<const float4*>(vol + r11 + (size_t)z * C_DIM);
    const float2 b11 = *reinterpret_cast<const float2*>(vol + r11 + (size_t)z2 * C_DIM);

    // Cell A (z): corners at z (a.xy) and z+1 (a.zw).
    uint4 Alo, Ahi;
    Alo.x = pack2(a00.x, a00.y);  Alo.y = pack2(a00.z, a00.w);
    Alo.z = pack2(a01.x, a01.y);  Alo.w = pack2(a01.z, a01.w);
    Ahi.x = pack2(a10.x, a10.y);  Ahi.y = pack2(a10.z, a10.w);
    Ahi.z = pack2(a11.x, a11.y);  Ahi.w = pack2(a11.z, a11.w);

    // Cell B (z+1): corners at z+1 (a.zw) and z+2 clamped (b).
    uint4 Blo, Bhi;
    Blo.x = pack2(a00.z, a00.w);  Blo.y = pack2(b00.x, b00.y);
    Blo.z = pack2(a01.z, a01.w);  Blo.w = pack2(b01.x, b01.y);
    Bhi.x = pack2(a10.z, a10.w);  Bhi.y = pack2(b10.x, b10.y);
    Bhi.z = pack2(a11.z, a11.w);  Bhi.w = pack2(b11.x, b11.y);

    const size_t cell = (size_t)b * SSS_DIM +
                        (size_t)(x * SS_DIM + y * S_DIM + z);
    uint4* dst = table + cell * 2;             // 64B-aligned (cell even)
    dst[0] = Alo;
    dst[1] = Ahi;
    dst[2] = Blo;
    dst[3] = Bhi;
}

// K2: one thread per output voxel; one 64B record load per sample.
// (Round-3 version — best measured at 123 us; at the random-fill ceiling.)
__global__ __launch_bounds__(256) void resample_from_table(
    const uint4* __restrict__ table, const float* __restrict__ def,
    float* __restrict__ out, int n_vox)
{
    int idx = blockIdx.x * blockDim.x + threadIdx.x;
    if (idx >= n_vox) return;

    const float dx = def[(size_t)idx * 3 + 0];
    const float dy = def[(size_t)idx * 3 + 1];
    const float dz = def[(size_t)idx * 3 + 2];

    const float fx = floorf(dx), fy = floorf(dy), fz = floorf(dz);
    const int ix = (int)fx, iy = (int)fy, iz = (int)fz;
    const float tx = dx - fx, ty = dy - fy, tz = dz - fz;

    // ZERO-boundary folded into the 1-D weights.
    const float ax0 = (ix     >= 0 && ix     < S_DIM) ? (1.0f - tx) : 0.0f;
    const float ax1 = (ix + 1 >= 0 && ix + 1 < S_DIM) ? tx          : 0.0f;
    const float ay0 = (iy     >= 0 && iy     < S_DIM) ? (1.0f - ty) : 0.0f;
    const float ay1 = (iy + 1 >= 0 && iy + 1 < S_DIM) ? ty          : 0.0f;
    const float az0 = (iz     >= 0 && iz     < S_DIM) ? (1.0f - tz) : 0.0f;
    const float az1 = (iz + 1 >= 0 && iz + 1 < S_DIM) ? tz          : 0.0f;

    const int cx = min(max(ix, 0), S_DIM - 1);
    const int cy = min(max(iy, 0), S_DIM - 1);
    const int cz = min(max(iz, 0), S_DIM - 1);
    const int b  = (idx >= SSS_DIM) ? 1 : 0;

    const size_t cell = (size_t)b * SSS_DIM + (size_t)(cx * SS_DIM + cy * S_DIM + cz);
    const uint4 lo = table[cell * 2];
    const uint4 hi = table[cell * 2 + 1];

    const float2 c000 = unpack2(lo.x), c001 = unpack2(lo.y);
    const float2 c010 = unpack2(lo.z), c011 = unpack2(lo.w);
    const float2 c100 = unpack2(hi.x), c101 = unpack2(hi.y);
    const float2 c110 = unpack2(hi.z), c111 = unpack2(hi.w);

    const float w000 = ax0 * ay0 * az0, w001 = ax0 * ay0 * az1;
    const float w010 = ax0 * ay1 * az0, w011 = ax0 * ay1 * az1;
    const float w100 = ax1 * ay0 * az0, w101 = ax1 * ay0 * az1;
    const float w110 = ax1 * ay1 * az0, w111 = ax1 * ay1 * az1;

    float acc0 = 0.0f, acc1 = 0.0f;
    acc0 = fmaf(w000, c000.x, acc0); acc1 = fmaf(w000, c000.y, acc1);
    acc0 = fmaf(w001, c001.x, acc0); acc1 = fmaf(w001, c001.y, acc1);
    acc0 = fmaf(w010, c010.x, acc0); acc1 = fmaf(w010, c010.y, acc1);
    acc0 = fmaf(w011, c011.x, acc0); acc1 = fmaf(w011, c011.y, acc1);
    acc0 = fmaf(w100, c100.x, acc0); acc1 = fmaf(w100, c100.y, acc1);
    acc0 = fmaf(w101, c101.x, acc0); acc1 = fmaf(w101, c101.y, acc1);
    acc0 = fmaf(w110, c110.x, acc0); acc1 = fmaf(w110, c110.y, acc1);
    acc0 = fmaf(w111, c111.x, acc0); acc1 = fmaf(w111, c111.y, acc1);

    reinterpret_cast<float2*>(out)[idx] = make_float2(acc0, acc1);
}

// Fallback (direct gather) if d_ws is too small for the table.
__global__ __launch_bounds__(256) void resample_trilinear_zero(
    const float* __restrict__ inp, const float* __restrict__ def,
    float* __restrict__ out, int n_vox)
{
    int idx = blockIdx.x * blockDim.x + threadIdx.x;
    if (idx >= n_vox) return;

    const int S = S_DIM;
    const int b = idx / SSS_DIM;

    const float dx = def[(size_t)idx * 3 + 0];
    const float dy = def[(size_t)idx * 3 + 1];
    const float dz = def[(size_t)idx * 3 + 2];

    const float fx = floorf(dx), fy = floorf(dy), fz = floorf(dz);
    const int ix = (int)fx, iy = (int)fy, iz = (int)fz;
    const float tx = dx - fx, ty = dy - fy, tz = dz - fz;

    const float wx[2] = {1.0f - tx, tx};
    const float wy[2] = {1.0f - ty, ty};
    const float wz[2] = {1.0f - tz, tz};

    const float* vol = inp + (size_t)b * SSS_DIM * C_DIM;
    float acc0 = 0.0f, acc1 = 0.0f;

#pragma unroll
    for (int a = 0; a < 2; ++a) {
        const int x = ix + a;
        const bool vx = (x >= 0) & (x < S);
        const int xc = min(max(x, 0), S - 1);
#pragma unroll
        for (int bb = 0; bb < 2; ++bb) {
            const int y = iy + bb;
            const bool vxy = vx & (y >= 0) & (y < S);
            const int yc = min(max(y, 0), S - 1);
            const float wxy = wx[a] * wy[bb];
#pragma unroll
            for (int cc = 0; cc < 2; ++cc) {
                const int z = iz + cc;
                const bool valid = vxy & (z >= 0) & (z < S);
                const int zc = min(max(z, 0), S - 1);
                const float w = valid ? wxy * wz[cc] : 0.0f;
                const float2 val = *reinterpret_cast<const float2*>(
                    vol + (size_t)(xc * SS_DIM + yc * S + zc) * C_DIM);
                acc0 = fmaf(w, val.x, acc0);
                acc1 = fmaf(w, val.y, acc1);
            }
        }
    }
    reinterpret_cast<float2*>(out)[idx] = make_float2(acc0, acc1);
}

extern "C" void kernel_launch(void* const* d_in, const int* in_sizes, int n_in,
                              void* d_out, int out_size, void* d_ws, size_t ws_size,
                              hipStream_t stream) {
    const float* inp = (const float*)d_in[0];
    const float* def = (const float*)d_in[1];
    float* out = (float*)d_out;

    const int n_vox = out_size / C_DIM;               // B * S^3 = 5,971,968
    const size_t table_bytes = (size_t)2 * SSS_DIM * 32;  // 191 MB

    const int block = 256;
    if (ws_size >= table_bytes) {
        uint4* table = (uint4*)d_ws;
        const int n_pairs = 2 * SS_DIM * (S_DIM / 2); // 2,985,984
        build_cell_table_pair<<<(n_pairs + block - 1) / block, block, 0, stream>>>(
            inp, table, n_pairs);
        resample_from_table<<<(n_vox + block - 1) / block, block, 0, stream>>>(
            table, def, out, n_vox);
    } else {
        resample_trilinear_zero<<<(n_vox + block - 1) / block, block, 0, stream>>>(
            inp, def, out, n_vox);
    }
}